// Round 1
// baseline (12234.186 us; speedup 1.0000x reference)
//
#include <hip/hip_runtime.h>
#include <math.h>

// Problem constants
constexpr int B_   = 64;
constexpr int L_   = 30;
constexpr int P_   = 196;
constexpr int ENC_ = 2048;
constexpr int E_   = 512;
constexpr int V_   = 10000;

__device__ __forceinline__ float wred_sum(float v) {
#pragma unroll
    for (int m = 32; m >= 1; m >>= 1) v += __shfl_xor(v, m, 64);
    return v;
}
__device__ __forceinline__ float sigmf(float x) { return 1.0f / (1.0f + expf(-x)); }
__device__ __forceinline__ float d4(float4 a, float4 b) {
    return a.x * b.x + a.y * b.y + a.z * b.z + a.w * b.w;
}

// ---------------------------------------------------------------------------
// k_init: mean over P for each (b, d).  grid=64 blocks (b), 256 thr.
// ---------------------------------------------------------------------------
__global__ __launch_bounds__(256) void k_init(const float* __restrict__ enc,
                                              float* __restrict__ mean) {
    int b = blockIdx.x, tid = threadIdx.x;
#pragma unroll
    for (int i = 0; i < 8; i++) {
        int d = tid + i * 256;
        const float* base = enc + (size_t)b * P_ * ENC_ + d;
        float s = 0.f;
        for (int p = 0; p < P_; p++) s += base[(size_t)p * ENC_];
        mean[(size_t)b * ENC_ + d] = s / 196.0f;
    }
}

// ---------------------------------------------------------------------------
// k_big: fp32 tiled GEMM  C[m,n] = bias[n] + sum_k A[m,k]*W[n,k],  K=2048.
// blocks 0..1567   : att1 = enc(12544x2048) @ We^T  -> (12544x512)
// blocks 1568..1575: h0   = mean(64x2048)  @ Wh0^T  -> (64x512)
// blocks 1576..1583: c0   = mean(64x2048)  @ Wc0^T  -> (64x512)
// 64x64 tile, BK=16, thread = 4x4 micro-tile.
// ---------------------------------------------------------------------------
__global__ __launch_bounds__(256) void k_big(
    const float* __restrict__ enc, const float* __restrict__ mean,
    const float* __restrict__ We, const float* __restrict__ be,
    const float* __restrict__ Wh0, const float* __restrict__ bh0,
    const float* __restrict__ Wc0, const float* __restrict__ bc0,
    float* __restrict__ att1, float* __restrict__ h0, float* __restrict__ c0) {
    __shared__ __align__(16) float As[16][68];
    __shared__ __align__(16) float Bs[16][68];
    int bi = blockIdx.x;
    const float* A; const float* W; const float* bias; float* C;
    int m0, n0;
    if (bi < 1568)      { A = enc;  W = We;  bias = be;  C = att1; m0 = (bi >> 3) << 6; n0 = (bi & 7) << 6; }
    else if (bi < 1576) { A = mean; W = Wh0; bias = bh0; C = h0;   m0 = 0; n0 = (bi - 1568) << 6; }
    else                { A = mean; W = Wc0; bias = bc0; C = c0;   m0 = 0; n0 = (bi - 1576) << 6; }

    int tid = threadIdx.x;
    int tx = tid & 15, ty = tid >> 4;
    int srow = tid >> 2, skq = tid & 3;
    float acc[4][4];
#pragma unroll
    for (int i = 0; i < 4; i++)
#pragma unroll
        for (int j = 0; j < 4; j++) acc[i][j] = 0.f;

    const float* Aptr = A + (size_t)(m0 + srow) * 2048 + skq * 4;
    const float* Wptr = W + (size_t)(n0 + srow) * 2048 + skq * 4;

    for (int kk = 0; kk < 2048; kk += 16) {
        float4 av = *(const float4*)(Aptr + kk);
        float4 wv = *(const float4*)(Wptr + kk);
        __syncthreads();
        As[skq * 4 + 0][srow] = av.x; As[skq * 4 + 1][srow] = av.y;
        As[skq * 4 + 2][srow] = av.z; As[skq * 4 + 3][srow] = av.w;
        Bs[skq * 4 + 0][srow] = wv.x; Bs[skq * 4 + 1][srow] = wv.y;
        Bs[skq * 4 + 2][srow] = wv.z; Bs[skq * 4 + 3][srow] = wv.w;
        __syncthreads();
#pragma unroll
        for (int k = 0; k < 16; k++) {
            float4 a4 = *(const float4*)(&As[k][ty * 4]);
            float4 b4 = *(const float4*)(&Bs[k][tx * 4]);
            float ar[4] = {a4.x, a4.y, a4.z, a4.w};
            float br[4] = {b4.x, b4.y, b4.z, b4.w};
#pragma unroll
            for (int i = 0; i < 4; i++)
#pragma unroll
                for (int j = 0; j < 4; j++) acc[i][j] = fmaf(ar[i], br[j], acc[i][j]);
        }
    }
#pragma unroll
    for (int i = 0; i < 4; i++) {
        int m = m0 + ty * 4 + i;
        float4 o;
        o.x = acc[i][0] + bias[n0 + tx * 4 + 0];
        o.y = acc[i][1] + bias[n0 + tx * 4 + 1];
        o.z = acc[i][2] + bias[n0 + tx * 4 + 2];
        o.w = acc[i][3] + bias[n0 + tx * 4 + 3];
        *(float4*)(C + (size_t)m * 512 + n0 + tx * 4) = o;
    }
}

// ---------------------------------------------------------------------------
// k_attn: per-batch block. att2 = h@Wd^T+bd; e[p] = relu(att1+att2)@Wf+bf;
// softmax over P; write atts output. grid=64 (b), 256 thr.
// ---------------------------------------------------------------------------
__global__ __launch_bounds__(256) void k_attn(
    const float* __restrict__ att1, const float* __restrict__ Wd,
    const float* __restrict__ bd, const float* __restrict__ Wf,
    const float* __restrict__ bfp, const float* __restrict__ h_cur,
    float* __restrict__ atts_out, int t) {
    __shared__ __align__(16) float h_s[512];
    __shared__ __align__(16) float att2_s[512];
    __shared__ __align__(16) float wf_s[512];
    __shared__ float e_s[256];
    __shared__ float red[256];
    int b = blockIdx.x, tid = threadIdx.x;
    int lane = tid & 63, wid = tid >> 6;
    h_s[tid] = h_cur[b * 512 + tid];
    h_s[tid + 256] = h_cur[b * 512 + 256 + tid];
    wf_s[tid] = Wf[tid];
    wf_s[tid + 256] = Wf[tid + 256];
    __syncthreads();
    const float4* h4 = (const float4*)h_s;
    float4 ha = h4[lane], hb = h4[lane + 64];
    for (int a = wid; a < 512; a += 4) {
        const float4* wr = (const float4*)(Wd + (size_t)a * 512);
        float s = d4(wr[lane], ha) + d4(wr[lane + 64], hb);
        s = wred_sum(s);
        if (lane == 0) att2_s[a] = s + bd[a];
    }
    __syncthreads();
    const float4* a24 = (const float4*)att2_s;
    const float4* wf4 = (const float4*)wf_s;
    float4 t0 = a24[lane], t1 = a24[lane + 64];
    float4 f0 = wf4[lane], f1 = wf4[lane + 64];
    for (int p = wid; p < P_; p += 4) {
        const float4* rr = (const float4*)(att1 + ((size_t)b * P_ + p) * 512);
        float4 v0 = rr[lane], v1 = rr[lane + 64];
        float s = fmaxf(v0.x + t0.x, 0.f) * f0.x + fmaxf(v0.y + t0.y, 0.f) * f0.y +
                  fmaxf(v0.z + t0.z, 0.f) * f0.z + fmaxf(v0.w + t0.w, 0.f) * f0.w +
                  fmaxf(v1.x + t1.x, 0.f) * f1.x + fmaxf(v1.y + t1.y, 0.f) * f1.y +
                  fmaxf(v1.z + t1.z, 0.f) * f1.z + fmaxf(v1.w + t1.w, 0.f) * f1.w;
        s = wred_sum(s);
        if (lane == 0) e_s[p] = s + bfp[0];
    }
    __syncthreads();
    // softmax over 196
    float val = (tid < P_) ? e_s[tid] : -INFINITY;
    red[tid] = val;
    __syncthreads();
    for (int s = 128; s > 0; s >>= 1) {
        if (tid < s) red[tid] = fmaxf(red[tid], red[tid + s]);
        __syncthreads();
    }
    float m = red[0];
    __syncthreads();
    float ex = (tid < P_) ? expf(val - m) : 0.f;
    red[tid] = ex;
    __syncthreads();
    for (int s = 128; s > 0; s >>= 1) {
        if (tid < s) red[tid] += red[tid + s];
        __syncthreads();
    }
    float sum = red[0];
    if (tid < P_) atts_out[((size_t)b * L_ + t) * P_ + tid] = ex / sum;
}

// ---------------------------------------------------------------------------
// k_ctx: ctx[b,d] = sum_p att[b,p] * enc[b,p,d].  grid=(8 dc, 64 b), 256 thr.
// ---------------------------------------------------------------------------
__global__ __launch_bounds__(256) void k_ctx(const float* __restrict__ enc,
                                             const float* __restrict__ atts_out,
                                             float* __restrict__ ctx, int t) {
    __shared__ float att_s[P_];
    int dc = blockIdx.x, b = blockIdx.y, tid = threadIdx.x;
    if (tid < P_) att_s[tid] = atts_out[((size_t)b * L_ + t) * P_ + tid];
    __syncthreads();
    int d = dc * 256 + tid;
    const float* base = enc + (size_t)b * P_ * ENC_ + d;
    float a0 = 0, a1 = 0, a2 = 0, a3 = 0;
    for (int p = 0; p < P_; p += 4) {
        a0 = fmaf(att_s[p + 0], base[(size_t)(p + 0) * ENC_], a0);
        a1 = fmaf(att_s[p + 1], base[(size_t)(p + 1) * ENC_], a1);
        a2 = fmaf(att_s[p + 2], base[(size_t)(p + 2) * ENC_], a2);
        a3 = fmaf(att_s[p + 3], base[(size_t)(p + 3) * ENC_], a3);
    }
    ctx[(size_t)b * ENC_ + d] = ((a0 + a1) + (a2 + a3));
}

// ---------------------------------------------------------------------------
// k_gates: finalize argmax (partials from prev k_logits), gather emb row,
// gates = [ctx,inp]@Wih^T + bih + h@Whh^T + bhh; LSTM cell update.
// grid=(8 jc, 64 b), 256 thr.  jc in blockIdx.x => per-XCD weight slice.
// ---------------------------------------------------------------------------
__global__ __launch_bounds__(256) void k_gates(
    const float* __restrict__ ctx, const float* __restrict__ emb,
    const int* __restrict__ dec_in, const float* __restrict__ Wih,
    const float* __restrict__ bih, const float* __restrict__ Whh,
    const float* __restrict__ bhh, const float* __restrict__ h_cur,
    const float* __restrict__ c_cur, float* __restrict__ h_nxt,
    float* __restrict__ c_nxt, const float* __restrict__ pval,
    const int* __restrict__ pidx, int t) {
    __shared__ __align__(16) float x_s[2560];
    __shared__ __align__(16) float h_s[512];
    __shared__ float g_s[256];
    __shared__ int tok_s;
    int jc = blockIdx.x, b = blockIdx.y, tid = threadIdx.x;
    int lane = tid & 63, wid = tid >> 6;
    if (tid == 0) {
        int tok;
        if (t == 0) {
            tok = dec_in[b * L_];
        } else {
            float bv_ = pval[b * 8]; int bi_ = pidx[b * 8];
            for (int q = 1; q < 8; q++) {
                float v = pval[b * 8 + q]; int ii = pidx[b * 8 + q];
                if (v > bv_) { bv_ = v; bi_ = ii; }
            }
            tok = bi_;
        }
        tok_s = tok;
    }
    for (int i = tid; i < 2048; i += 256) x_s[i] = ctx[(size_t)b * 2048 + i];
    for (int i = tid; i < 512; i += 256) h_s[i] = h_cur[b * 512 + i];
    __syncthreads();
    for (int i = tid; i < 512; i += 256) x_s[2048 + i] = emb[(size_t)tok_s * 512 + i];
    __syncthreads();
    const float4* x4 = (const float4*)x_s;
    const float4* h4 = (const float4*)h_s;
    for (int o = wid; o < 256; o += 4) {
        int jl = o >> 2, gate = o & 3;
        int n = gate * 512 + jc * 64 + jl;
        const float4* wi = (const float4*)(Wih + (size_t)n * 2560);
        float s = 0.f;
#pragma unroll
        for (int i = 0; i < 10; i++) s += d4(wi[lane + 64 * i], x4[lane + 64 * i]);
        const float4* wh = (const float4*)(Whh + (size_t)n * 512);
        s += d4(wh[lane], h4[lane]) + d4(wh[lane + 64], h4[lane + 64]);
        s = wred_sum(s);
        if (lane == 0) g_s[gate * 64 + jl] = s + bih[n] + bhh[n];
    }
    __syncthreads();
    if (tid < 64) {
        int j = jc * 64 + tid;
        float iv = g_s[0 * 64 + tid], fv = g_s[64 + tid];
        float gv = g_s[128 + tid], ov = g_s[192 + tid];
        float cold = c_cur[b * 512 + j];
        float cn = sigmf(fv) * cold + sigmf(iv) * tanhf(gv);
        float hn = sigmf(ov) * tanhf(cn);
        c_nxt[b * 512 + j] = cn;
        h_nxt[b * 512 + j] = hn;
    }
}

// ---------------------------------------------------------------------------
// k_logits: logits = h@Wv^T + bv -> out[(b,t,:)]; per-block argmax partial.
// grid=(8 vc, 64 b), 256 thr.  vc in blockIdx.x => per-XCD Wv slice.
// ---------------------------------------------------------------------------
__global__ __launch_bounds__(256) void k_logits(
    const float* __restrict__ Wv, const float* __restrict__ bv,
    const float* __restrict__ h_nxt, float* __restrict__ out,
    float* __restrict__ pval, int* __restrict__ pidx, int t) {
    __shared__ __align__(16) float h_s[512];
    __shared__ float bvs[4];
    __shared__ int bis[4];
    int vc = blockIdx.x, b = blockIdx.y, tid = threadIdx.x;
    int lane = tid & 63, wid = tid >> 6;
    h_s[tid] = h_nxt[b * 512 + tid];
    h_s[tid + 256] = h_nxt[b * 512 + 256 + tid];
    __syncthreads();
    const float4* h4 = (const float4*)h_s;
    float4 ha = h4[lane], hb = h4[lane + 64];
    int v0 = vc * 1250;
    float best = -INFINITY;
    int besti = 0;
    float* orow = out + ((size_t)b * L_ + t) * V_;
    for (int o = wid; o < 1250; o += 4) {
        int v = v0 + o;
        const float4* wr = (const float4*)(Wv + (size_t)v * 512);
        float s = d4(wr[lane], ha) + d4(wr[lane + 64], hb);
        s = wred_sum(s);
        float logit = s + bv[v];
        if (lane == 0) orow[v] = logit;
        if (logit > best) { best = logit; besti = v; }  // increasing v -> first max wins
    }
    if (lane == 0) { bvs[wid] = best; bis[wid] = besti; }
    __syncthreads();
    if (tid == 0) {
        float Bv = bvs[0]; int Ii = bis[0];
        for (int w = 1; w < 4; w++) {
            if (bvs[w] > Bv || (bvs[w] == Bv && bis[w] < Ii)) { Bv = bvs[w]; Ii = bis[w]; }
        }
        pval[b * 8 + vc] = Bv;
        pidx[b * 8 + vc] = Ii;
    }
}

// ---------------------------------------------------------------------------
extern "C" void kernel_launch(void* const* d_in, const int* in_sizes, int n_in,
                              void* d_out, int out_size, void* d_ws, size_t ws_size,
                              hipStream_t stream) {
    const float* enc = (const float*)d_in[0];
    const int* dec   = (const int*)d_in[1];
    // d_in[2] = epoch (unused)
    const float* emb = (const float*)d_in[3];
    const float* We  = (const float*)d_in[4];
    const float* be  = (const float*)d_in[5];
    const float* Wd  = (const float*)d_in[6];
    const float* bd  = (const float*)d_in[7];
    const float* Wf  = (const float*)d_in[8];
    const float* bf  = (const float*)d_in[9];
    const float* Wih = (const float*)d_in[10];
    const float* bih = (const float*)d_in[11];
    const float* Whh = (const float*)d_in[12];
    const float* bhh = (const float*)d_in[13];
    const float* Wh0 = (const float*)d_in[14];
    const float* bh0 = (const float*)d_in[15];
    const float* Wc0 = (const float*)d_in[16];
    const float* bc0 = (const float*)d_in[17];
    const float* Wv  = (const float*)d_in[18];
    const float* bv  = (const float*)d_in[19];

    float* out = (float*)d_out;
    float* ws = (float*)d_ws;

    // workspace layout (floats)
    float* att1 = ws;                  // 12544*512      = 6,422,528
    float* mean = att1 + 6422528;      // 64*2048        =   131,072
    float* ctx  = mean + 131072;       // 64*2048        =   131,072
    float* hbuf = ctx + 131072;        // 2 * 64*512     =    65,536
    float* cbuf = hbuf + 65536;        // 2 * 64*512     =    65,536
    float* pval = cbuf + 65536;        // 64*8           =       512
    int*   pidx = (int*)(pval + 512);  // 64*8           =       512

    float* atts_out = out + (size_t)B_ * L_ * V_;

    hipLaunchKernelGGL(k_init, dim3(64), dim3(256), 0, stream, enc, mean);
    hipLaunchKernelGGL(k_big, dim3(1584), dim3(256), 0, stream, enc, mean, We, be,
                       Wh0, bh0, Wc0, bc0, att1, hbuf, cbuf);

    for (int t = 0; t < L_; t++) {
        float* h_cur = hbuf + (t & 1) * 32768;
        float* h_nxt = hbuf + ((t + 1) & 1) * 32768;
        float* c_cur = cbuf + (t & 1) * 32768;
        float* c_nxt = cbuf + ((t + 1) & 1) * 32768;
        hipLaunchKernelGGL(k_attn, dim3(64), dim3(256), 0, stream, att1, Wd, bd, Wf,
                           bf, h_cur, atts_out, t);
        hipLaunchKernelGGL(k_ctx, dim3(8, 64), dim3(256), 0, stream, enc, atts_out,
                           ctx, t);
        hipLaunchKernelGGL(k_gates, dim3(8, 64), dim3(256), 0, stream, ctx, emb, dec,
                           Wih, bih, Whh, bhh, h_cur, c_cur, h_nxt, c_nxt, pval,
                           pidx, t);
        hipLaunchKernelGGL(k_logits, dim3(8, 64), dim3(256), 0, stream, Wv, bv,
                           h_nxt, out, pval, pidx, t);
    }
}

// Round 3
// 10251.310 us; speedup vs baseline: 1.1934x; 1.1934x over previous
//
#include <hip/hip_runtime.h>
#include <math.h>

constexpr int B_   = 64;
constexpr int L_   = 30;
constexpr int P_   = 196;
constexpr int ENC_ = 2048;
constexpr int V_   = 10000;
constexpr int XSTR = 3072;   // X row: [ctx 2048 | emb 512 | h 512]

__device__ __forceinline__ float wred_sum(float v) {
#pragma unroll
    for (int m = 32; m >= 1; m >>= 1) v += __shfl_xor(v, m, 64);
    return v;
}
__device__ __forceinline__ float sigmf(float x) { return 1.0f / (1.0f + expf(-x)); }
// 16-term dot: w[4] (registers) . x[16] (pointer, 16B-aligned)
__device__ __forceinline__ float dot16(const float4* w, const float* xp) {
    const float4* x4 = (const float4*)xp;
    float4 x0 = x4[0], x1 = x4[1], x2 = x4[2], x3 = x4[3];
    float s = w[0].x * x0.x;
    s = fmaf(w[0].y, x0.y, s); s = fmaf(w[0].z, x0.z, s); s = fmaf(w[0].w, x0.w, s);
    s = fmaf(w[1].x, x1.x, s); s = fmaf(w[1].y, x1.y, s);
    s = fmaf(w[1].z, x1.z, s); s = fmaf(w[1].w, x1.w, s);
    s = fmaf(w[2].x, x2.x, s); s = fmaf(w[2].y, x2.y, s);
    s = fmaf(w[2].z, x2.z, s); s = fmaf(w[2].w, x2.w, s);
    s = fmaf(w[3].x, x3.x, s); s = fmaf(w[3].y, x3.y, s);
    s = fmaf(w[3].z, x3.z, s); s = fmaf(w[3].w, x3.w, s);
    return s;
}

// ---------------------------------------------------------------------------
// k_init: mean over P.  grid=(8,64), 256 thr.
// ---------------------------------------------------------------------------
__global__ __launch_bounds__(256) void k_init(const float* __restrict__ enc,
                                              float* __restrict__ mean) {
    int dc = blockIdx.x, b = blockIdx.y, d = dc * 256 + threadIdx.x;
    const float* base = enc + (size_t)b * P_ * ENC_ + d;
    float s = 0.f;
    for (int p = 0; p < P_; p++) s += base[(size_t)p * ENC_];
    mean[(size_t)b * ENC_ + d] = s / 196.0f;
}

// ---------------------------------------------------------------------------
// k_big: fp32 GEMM, 128x128 tile, BK=16, split 8x8 micro-tile.
// blocks 0..391: att1 = enc @ We^T ; 392..395: h0 -> X h-slot ; 396..399: c0.
// ---------------------------------------------------------------------------
__global__ __launch_bounds__(256) void k_big(
    const float* __restrict__ enc, const float* __restrict__ mean,
    const float* __restrict__ We, const float* __restrict__ be,
    const float* __restrict__ Wh0, const float* __restrict__ bh0,
    const float* __restrict__ Wc0, const float* __restrict__ bc0,
    float* __restrict__ att1, float* __restrict__ X, float* __restrict__ cbuf) {
    __shared__ __align__(16) float As[16][132];
    __shared__ __align__(16) float Ws[16][132];
    int gx = blockIdx.x;
    const float *A, *W, *bias;
    float* C;
    int m0, n0, Mtot, cstr;
    if (gx < 392) {
        A = enc; W = We; bias = be; C = att1;
        m0 = (gx >> 2) * 128; n0 = (gx & 3) * 128; Mtot = 12544; cstr = 512;
    } else if (gx < 396) {
        A = mean; W = Wh0; bias = bh0; C = X + 2560;
        m0 = 0; n0 = (gx - 392) * 128; Mtot = 64; cstr = XSTR;
    } else {
        A = mean; W = Wc0; bias = bc0; C = cbuf;
        m0 = 0; n0 = (gx - 396) * 128; Mtot = 64; cstr = 512;
    }
    int tid = threadIdx.x, tx = tid & 15, ty = tid >> 4;
    int srow = tid >> 2, skq = tid & 3;
    float acc[2][2][4][4] = {};
    int r0 = m0 + min(srow, Mtot - 1);
    int r1 = m0 + min(srow + 64, Mtot - 1);
    const float* a0p = A + (size_t)r0 * 2048 + skq * 4;
    const float* a1p = A + (size_t)r1 * 2048 + skq * 4;
    const float* w0p = W + (size_t)(n0 + srow) * 2048 + skq * 4;
    const float* w1p = W + (size_t)(n0 + srow + 64) * 2048 + skq * 4;
    for (int kk = 0; kk < 2048; kk += 16) {
        float4 a0v = *(const float4*)(a0p + kk);
        float4 a1v = *(const float4*)(a1p + kk);
        float4 w0v = *(const float4*)(w0p + kk);
        float4 w1v = *(const float4*)(w1p + kk);
        __syncthreads();
        As[skq * 4 + 0][srow] = a0v.x; As[skq * 4 + 1][srow] = a0v.y;
        As[skq * 4 + 2][srow] = a0v.z; As[skq * 4 + 3][srow] = a0v.w;
        As[skq * 4 + 0][srow + 64] = a1v.x; As[skq * 4 + 1][srow + 64] = a1v.y;
        As[skq * 4 + 2][srow + 64] = a1v.z; As[skq * 4 + 3][srow + 64] = a1v.w;
        Ws[skq * 4 + 0][srow] = w0v.x; Ws[skq * 4 + 1][srow] = w0v.y;
        Ws[skq * 4 + 2][srow] = w0v.z; Ws[skq * 4 + 3][srow] = w0v.w;
        Ws[skq * 4 + 0][srow + 64] = w1v.x; Ws[skq * 4 + 1][srow + 64] = w1v.y;
        Ws[skq * 4 + 2][srow + 64] = w1v.z; Ws[skq * 4 + 3][srow + 64] = w1v.w;
        __syncthreads();
#pragma unroll
        for (int k = 0; k < 16; k++) {
            float4 av0 = *(const float4*)&As[k][ty * 4];
            float4 av1 = *(const float4*)&As[k][64 + ty * 4];
            float4 bv0 = *(const float4*)&Ws[k][tx * 4];
            float4 bv1 = *(const float4*)&Ws[k][64 + tx * 4];
            float ar[2][4] = {{av0.x, av0.y, av0.z, av0.w}, {av1.x, av1.y, av1.z, av1.w}};
            float br[2][4] = {{bv0.x, bv0.y, bv0.z, bv0.w}, {bv1.x, bv1.y, bv1.z, bv1.w}};
#pragma unroll
            for (int ih = 0; ih < 2; ih++)
#pragma unroll
                for (int jh = 0; jh < 2; jh++)
#pragma unroll
                    for (int i = 0; i < 4; i++)
#pragma unroll
                        for (int j = 0; j < 4; j++)
                            acc[ih][jh][i][j] = fmaf(ar[ih][i], br[jh][j], acc[ih][jh][i][j]);
        }
    }
#pragma unroll
    for (int ih = 0; ih < 2; ih++)
#pragma unroll
        for (int i = 0; i < 4; i++) {
            int m = m0 + ih * 64 + ty * 4 + i;
            if (m - m0 < Mtot) {
#pragma unroll
                for (int jh = 0; jh < 2; jh++) {
                    int n = n0 + jh * 64 + tx * 4;
                    float4 o;
                    o.x = acc[ih][jh][i][0] + bias[n + 0];
                    o.y = acc[ih][jh][i][1] + bias[n + 1];
                    o.z = acc[ih][jh][i][2] + bias[n + 2];
                    o.w = acc[ih][jh][i][3] + bias[n + 3];
                    *(float4*)(C + (size_t)m * cstr + n) = o;
                }
            }
        }
}

// ---------------------------------------------------------------------------
// k_emb0: X emb-slot <- emb[dec_in[:,0]].  grid=64, 256 thr.
// ---------------------------------------------------------------------------
__global__ __launch_bounds__(256) void k_emb0(const float* __restrict__ emb,
                                              const int* __restrict__ dec,
                                              float* __restrict__ X) {
    int b = blockIdx.x, tid = threadIdx.x;
    int tok = dec[b * L_];
    X[(size_t)b * XSTR + 2048 + tid] = emb[(size_t)tok * 512 + tid];
    X[(size_t)b * XSTR + 2048 + 256 + tid] = emb[(size_t)tok * 512 + 256 + tid];
}

// ---------------------------------------------------------------------------
// k_att2: direct  att2[b][n] = bd[n] + sum_k h[b][k]*Wd[n][k].
// grid=(8 nt, 8 bg), 64 thr.  lane = n, acc[8] over batch group.
// ---------------------------------------------------------------------------
__global__ __launch_bounds__(64) void k_att2(const float* __restrict__ X,
                                             const float* __restrict__ Wd,
                                             const float* __restrict__ bd,
                                             float* __restrict__ att2) {
    int nt = blockIdx.x, bg = blockIdx.y, lane = threadIdx.x;
    int n = nt * 64 + lane;
    const float* wrow = Wd + (size_t)n * 512;
    const float* xbase = X + 2560 + (size_t)bg * 8 * XSTR;
    float acc[8];
#pragma unroll
    for (int b = 0; b < 8; b++) acc[b] = 0.f;
#pragma unroll 1
    for (int k16 = 0; k16 < 512; k16 += 16) {
        float4 w[4];
        w[0] = *(const float4*)(wrow + k16);
        w[1] = *(const float4*)(wrow + k16 + 4);
        w[2] = *(const float4*)(wrow + k16 + 8);
        w[3] = *(const float4*)(wrow + k16 + 12);
        const float* xc = xbase + k16;
#pragma unroll
        for (int b = 0; b < 8; b++)
            acc[b] += dot16(w, xc + (size_t)b * XSTR);
    }
    float bias = bd[n];
#pragma unroll
    for (int b = 0; b < 8; b++)
        att2[(size_t)(bg * 8 + b) * 512 + n] = acc[b] + bias;
}

// ---------------------------------------------------------------------------
// k_soft: e = relu(att1+att2)@Wf + bf; softmax over P; write atts.
// grid=64 (b), 256 thr.
// ---------------------------------------------------------------------------
__global__ __launch_bounds__(256) void k_soft(
    const float* __restrict__ att1, const float* __restrict__ att2,
    const float* __restrict__ Wf, const float* __restrict__ bfp,
    float* __restrict__ atts_out, int t) {
    __shared__ __align__(16) float att2_s[512];
    __shared__ __align__(16) float wf_s[512];
    __shared__ float e_s[256];
    __shared__ float red[256];
    int b = blockIdx.x, tid = threadIdx.x;
    int lane = tid & 63, wid = tid >> 6;
    att2_s[tid] = att2[(size_t)b * 512 + tid];
    att2_s[tid + 256] = att2[(size_t)b * 512 + 256 + tid];
    wf_s[tid] = Wf[tid];
    wf_s[tid + 256] = Wf[tid + 256];
    __syncthreads();
    const float4* a24 = (const float4*)att2_s;
    const float4* wf4 = (const float4*)wf_s;
    float4 t0 = a24[lane], t1 = a24[lane + 64];
    float4 f0 = wf4[lane], f1 = wf4[lane + 64];
    for (int p = wid; p < P_; p += 4) {
        const float4* rr = (const float4*)(att1 + ((size_t)b * P_ + p) * 512);
        float4 v0 = rr[lane], v1 = rr[lane + 64];
        float s = fmaxf(v0.x + t0.x, 0.f) * f0.x + fmaxf(v0.y + t0.y, 0.f) * f0.y +
                  fmaxf(v0.z + t0.z, 0.f) * f0.z + fmaxf(v0.w + t0.w, 0.f) * f0.w +
                  fmaxf(v1.x + t1.x, 0.f) * f1.x + fmaxf(v1.y + t1.y, 0.f) * f1.y +
                  fmaxf(v1.z + t1.z, 0.f) * f1.z + fmaxf(v1.w + t1.w, 0.f) * f1.w;
        s = wred_sum(s);
        if (lane == 0) e_s[p] = s + bfp[0];
    }
    __syncthreads();
    float val = (tid < P_) ? e_s[tid] : -INFINITY;
    red[tid] = val;
    __syncthreads();
    for (int s = 128; s > 0; s >>= 1) {
        if (tid < s) red[tid] = fmaxf(red[tid], red[tid + s]);
        __syncthreads();
    }
    float m = red[0];
    __syncthreads();
    float ex = (tid < P_) ? expf(val - m) : 0.f;
    red[tid] = ex;
    __syncthreads();
    for (int s = 128; s > 0; s >>= 1) {
        if (tid < s) red[tid] += red[tid + s];
        __syncthreads();
    }
    float sum = red[0];
    if (tid < P_) atts_out[((size_t)b * L_ + t) * P_ + tid] = ex / sum;
}

// ---------------------------------------------------------------------------
// k_ctx: ctx[b,d] = sum_p att[b,p]*enc[b,p,d] -> X ctx-slot. grid=(8,64),256.
// ---------------------------------------------------------------------------
__global__ __launch_bounds__(256) void k_ctx(const float* __restrict__ enc,
                                             const float* __restrict__ atts_out,
                                             float* __restrict__ X, int t) {
    __shared__ float att_s[P_];
    int dc = blockIdx.x, b = blockIdx.y, tid = threadIdx.x;
    if (tid < P_) att_s[tid] = atts_out[((size_t)b * L_ + t) * P_ + tid];
    __syncthreads();
    int d = dc * 256 + tid;
    const float* base = enc + (size_t)b * P_ * ENC_ + d;
    float a0 = 0, a1 = 0, a2 = 0, a3 = 0;
    for (int p = 0; p < P_; p += 4) {
        a0 = fmaf(att_s[p + 0], base[(size_t)(p + 0) * ENC_], a0);
        a1 = fmaf(att_s[p + 1], base[(size_t)(p + 1) * ENC_], a1);
        a2 = fmaf(att_s[p + 2], base[(size_t)(p + 2) * ENC_], a2);
        a3 = fmaf(att_s[p + 3], base[(size_t)(p + 3) * ENC_], a3);
    }
    X[(size_t)b * XSTR + d] = ((a0 + a1) + (a2 + a3));
}

// ---------------------------------------------------------------------------
// k_gates: B-stationary partial GEMM over K=[Wih(2560)|Whh(512)], runtime
// chunking.  grid=(kc_count, 32 nt), 64 thr.  pg[kc][b][n] partials.
// ---------------------------------------------------------------------------
__global__ __launch_bounds__(64) void k_gates(const float* __restrict__ X,
                                              const float* __restrict__ Wih,
                                              const float* __restrict__ Whh,
                                              float* __restrict__ pg, int chunk) {
    int kc = blockIdx.x, nt = blockIdx.y, lane = threadIdx.x;
    int row = nt * 64 + lane;
    const float* wih_row = Wih + (size_t)row * 2560;
    const float* whh_row = Whh + (size_t)row * 512;
    int kbase = kc * chunk;
    const float* xbase = X + kbase;
    float acc[64];
#pragma unroll
    for (int b = 0; b < 64; b++) acc[b] = 0.f;
#pragma unroll 1
    for (int k16 = 0; k16 < chunk; k16 += 16) {
        int kk = kbase + k16;
        const float* wr = (kk < 2560) ? (wih_row + kk) : (whh_row + (kk - 2560));
        float4 w[4];
        w[0] = *(const float4*)(wr);
        w[1] = *(const float4*)(wr + 4);
        w[2] = *(const float4*)(wr + 8);
        w[3] = *(const float4*)(wr + 12);
        const float* xc = xbase + k16;
#pragma unroll
        for (int b = 0; b < 64; b++)
            acc[b] += dot16(w, xc + (size_t)b * XSTR);
    }
#pragma unroll
    for (int b = 0; b < 64; b++)
        pg[((size_t)kc * 64 + b) * 2048 + row] = acc[b];
}

// ---------------------------------------------------------------------------
// k_lstm: sum gate partials + biases, LSTM cell, h -> X h-slot, c in place.
// grid=64 (b), 512 thr.
// ---------------------------------------------------------------------------
__global__ __launch_bounds__(512) void k_lstm(const float* __restrict__ pg,
                                              const float* __restrict__ bih,
                                              const float* __restrict__ bhh,
                                              float* __restrict__ X,
                                              float* __restrict__ cbuf,
                                              int kc_count) {
    int b = blockIdx.x, j = threadIdx.x;
    float g[4];
#pragma unroll
    for (int gi = 0; gi < 4; gi++) {
        int n = gi * 512 + j;
        float s = bih[n] + bhh[n];
        for (int kc = 0; kc < kc_count; kc++)
            s += pg[((size_t)kc * 64 + b) * 2048 + n];
        g[gi] = s;
    }
    float c = cbuf[b * 512 + j];
    float cn = sigmf(g[1]) * c + sigmf(g[0]) * tanhf(g[2]);
    float hn = sigmf(g[3]) * tanhf(cn);
    cbuf[b * 512 + j] = cn;
    X[(size_t)b * XSTR + 2560 + j] = hn;
}

// ---------------------------------------------------------------------------
// k_logits: direct  out[b,t,v] = bv[v] + h[b]·Wv[v].  No scratch.
// grid=(157 nt, 4 bg), 64 thr.  lane = v, acc[16] over batch group.
// ---------------------------------------------------------------------------
__global__ __launch_bounds__(64) void k_logits(const float* __restrict__ X,
                                               const float* __restrict__ Wv,
                                               const float* __restrict__ bv,
                                               float* __restrict__ out, int t) {
    int nt = blockIdx.x, bg = blockIdx.y, lane = threadIdx.x;
    int v = nt * 64 + lane;
    int vr = min(v, V_ - 1);
    const float* wrow = Wv + (size_t)vr * 512;
    const float* xbase = X + 2560 + (size_t)bg * 16 * XSTR;
    float acc[16];
#pragma unroll
    for (int b = 0; b < 16; b++) acc[b] = 0.f;
#pragma unroll 1
    for (int k16 = 0; k16 < 512; k16 += 16) {
        float4 w[4];
        w[0] = *(const float4*)(wrow + k16);
        w[1] = *(const float4*)(wrow + k16 + 4);
        w[2] = *(const float4*)(wrow + k16 + 8);
        w[3] = *(const float4*)(wrow + k16 + 12);
        const float* xc = xbase + k16;
#pragma unroll
        for (int b = 0; b < 16; b++)
            acc[b] += dot16(w, xc + (size_t)b * XSTR);
    }
    if (v < V_) {
        float bias = bv[v];
#pragma unroll
        for (int b = 0; b < 16; b++) {
            int bb = bg * 16 + b;
            out[((size_t)bb * L_ + t) * V_ + v] = acc[b] + bias;
        }
    }
}

// ---------------------------------------------------------------------------
// k_fin: argmax over out row (logits incl bias); emb gather -> X emb-slot.
// grid=64 (b), 256 thr.
// ---------------------------------------------------------------------------
__global__ __launch_bounds__(256) void k_fin(const float* __restrict__ out,
                                             const float* __restrict__ emb,
                                             float* __restrict__ X, int t) {
    __shared__ float mv[256];
    __shared__ int mi[256];
    int b = blockIdx.x, tid = threadIdx.x;
    float best = -INFINITY;
    int besti = 0;
    const float* orow = out + ((size_t)b * L_ + t) * V_;
    for (int v = tid; v < V_; v += 256) {
        float s = orow[v];
        if (s > best) { best = s; besti = v; }
    }
    mv[tid] = best;
    mi[tid] = besti;
    __syncthreads();
    for (int s = 128; s > 0; s >>= 1) {
        if (tid < s) {
            if (mv[tid + s] > mv[tid] ||
                (mv[tid + s] == mv[tid] && mi[tid + s] < mi[tid])) {
                mv[tid] = mv[tid + s];
                mi[tid] = mi[tid + s];
            }
        }
        __syncthreads();
    }
    int tok = mi[0];
    X[(size_t)b * XSTR + 2048 + tid] = emb[(size_t)tok * 512 + tid];
    X[(size_t)b * XSTR + 2048 + 256 + tid] = emb[(size_t)tok * 512 + 256 + tid];
}

// ---------------------------------------------------------------------------
extern "C" void kernel_launch(void* const* d_in, const int* in_sizes, int n_in,
                              void* d_out, int out_size, void* d_ws, size_t ws_size,
                              hipStream_t stream) {
    const float* enc = (const float*)d_in[0];
    const int* dec   = (const int*)d_in[1];
    const float* emb = (const float*)d_in[3];
    const float* We  = (const float*)d_in[4];
    const float* be  = (const float*)d_in[5];
    const float* Wd  = (const float*)d_in[6];
    const float* bd  = (const float*)d_in[7];
    const float* Wf  = (const float*)d_in[8];
    const float* bf  = (const float*)d_in[9];
    const float* Wih = (const float*)d_in[10];
    const float* bih = (const float*)d_in[11];
    const float* Whh = (const float*)d_in[12];
    const float* bhh = (const float*)d_in[13];
    const float* Wh0 = (const float*)d_in[14];
    const float* bh0 = (const float*)d_in[15];
    const float* Wc0 = (const float*)d_in[16];
    const float* bc0 = (const float*)d_in[17];
    const float* Wv  = (const float*)d_in[18];
    const float* bv  = (const float*)d_in[19];

    float* out = (float*)d_out;
    float* ws = (float*)d_ws;

    // workspace layout (floats) — adaptive to ws_size
    float* att1 = ws;              // 6,422,528
    float* X    = att1 + 6422528;  //   196,608
    float* cbuf = X + 196608;      //    32,768
    float* pg   = cbuf + 32768;    // kc_count * 131,072 (gate partials)
    float* mean = pg;              // alias: setup only (needs kc_count>=1)
    float* att2 = pg;              // alias: dead before k_gates writes pg

    const size_t base_fl = 6422528 + 196608 + 32768;  // 6,651,904
    size_t avail_fl = ws_size / 4;
    int kc_count = 1, chunk = 3072;
    const int opt_kc[5] = {24, 12, 6, 3, 2};
    const int opt_ck[5] = {128, 256, 512, 1024, 1536};
    for (int i = 0; i < 5; i++) {
        if (avail_fl >= base_fl + (size_t)opt_kc[i] * 131072) {
            kc_count = opt_kc[i];
            chunk = opt_ck[i];
            break;
        }
    }

    float* atts_out = out + (size_t)B_ * L_ * V_;

    hipLaunchKernelGGL(k_init, dim3(8, 64), dim3(256), 0, stream, enc, mean);
    hipLaunchKernelGGL(k_big, dim3(400), dim3(256), 0, stream, enc, mean, We, be,
                       Wh0, bh0, Wc0, bc0, att1, X, cbuf);
    hipLaunchKernelGGL(k_emb0, dim3(64), dim3(256), 0, stream, emb, dec, X);

    for (int t = 0; t < L_; t++) {
        hipLaunchKernelGGL(k_att2, dim3(8, 8), dim3(64), 0, stream, X, Wd, bd, att2);
        hipLaunchKernelGGL(k_soft, dim3(64), dim3(256), 0, stream, att1, att2, Wf,
                           bf, atts_out, t);
        hipLaunchKernelGGL(k_ctx, dim3(8, 64), dim3(256), 0, stream, enc, atts_out,
                           X, t);
        hipLaunchKernelGGL(k_gates, dim3(kc_count, 32), dim3(64), 0, stream, X, Wih,
                           Whh, pg, chunk);
        hipLaunchKernelGGL(k_lstm, dim3(64), dim3(512), 0, stream, pg, bih, bhh, X,
                           cbuf, kc_count);
        hipLaunchKernelGGL(k_logits, dim3(157, 4), dim3(64), 0, stream, X, Wv, bv,
                           out, t);
        hipLaunchKernelGGL(k_fin, dim3(64), dim3(256), 0, stream, out, emb, X, t);
    }
}